// Round 8
// baseline (229.588 us; speedup 1.0000x reference)
//
#include <hip/hip_runtime.h>
#include <stdint.h>

// Problem constants
#define NHEAD 12
#define HDIM  64
#define EMB   768
#define N3    2304      // 3*EMB
#define SEQ   2048
#define BATCH 4
#define MROWS 8192      // BATCH*SEQ

// 0.125 * log2(e): folds the 1/sqrt(64) scale AND the e->2 base change into Q.
#define QSCALE 0.18033688011112042f

typedef __bf16 bf16_t;
typedef __bf16 bf16x8 __attribute__((ext_vector_type(8)));
typedef __bf16 bf16x4 __attribute__((ext_vector_type(4)));
typedef short  s16x4  __attribute__((ext_vector_type(4)));
typedef float  f32x4  __attribute__((ext_vector_type(4)));

// async global->LDS, 16 B/lane. HW scatters lane i to (readfirstlane(lds)) + i*16.
__device__ __forceinline__ void gld_lds16(void* lds, const void* g) {
    __builtin_amdgcn_global_load_lds((const __attribute__((address_space(1))) void*)g,
                                     (__attribute__((address_space(3))) void*)lds,
                                     16, 0, 0);
}

// raw v_exp_f32 (2^x): args are provably in-range; skips libm denormal fixup.
__device__ __forceinline__ float fast_exp2(float x) {
    return __builtin_amdgcn_exp2f(x);
}

// 16x16x16 bf16 MFMA (K=16): A 2 VGPR / B 2 VGPR / C-D 4 (cdna4_isa §10).
__device__ __forceinline__ f32x4 mfma16_bf16(bf16x4 a, bf16x4 b, f32x4 c) {
#if __has_builtin(__builtin_amdgcn_mfma_f32_16x16x16_bf16)
    return __builtin_amdgcn_mfma_f32_16x16x16_bf16(a, b, c, 0, 0, 0);
#else
    union U { bf16x4 h; s16x4 s; };
    U ua, ub; ua.h = a; ub.h = b;
    return __builtin_amdgcn_mfma_f32_16x16x16bf16_1k(ua.s, ub.s, c, 0, 0, 0);
#endif
}

// ---------------------------------------------------------------------------
// Fused prep: one launch does
//   blocks [0,1728)    : W_attn [768][2304] -> WaT [2304][768] bf16 (32x32 tiles)
//   blocks [1728,2304) : W_proj [768][768]  -> WpT [768][768]  bf16
//   blocks [2304,3840) : x fp32 -> bf16 streaming convert
// ---------------------------------------------------------------------------
__global__ __launch_bounds__(256) void prep_kernel(
    const float* __restrict__ Wa, bf16_t* __restrict__ WaT,
    const float* __restrict__ Wp, bf16_t* __restrict__ WpT,
    const float* __restrict__ x,  bf16_t* __restrict__ xb)
{
    __shared__ float tile[32][33];
    const int bid = blockIdx.x;
    if (bid < 2304) {
        // transpose+convert job
        const float* W; bf16_t* WT; int K, N, b;
        if (bid < 1728) { W = Wa; WT = WaT; K = 768; N = 2304; b = bid; }
        else            { W = Wp; WT = WpT; K = 768; N = 768;  b = bid - 1728; }
        const int nb = N / 32;
        const int n0 = (b % nb) * 32, k0 = (b / nb) * 32;
        const int tx = threadIdx.x & 31, ty = threadIdx.x >> 5;   // ty 0..7
#pragma unroll
        for (int i = 0; i < 32; i += 8)
            tile[ty + i][tx] = W[(size_t)(k0 + ty + i) * N + (n0 + tx)];
        __syncthreads();
#pragma unroll
        for (int i = 0; i < 32; i += 8)
            WT[(size_t)(n0 + ty + i) * K + (k0 + tx)] = (bf16_t)tile[tx][ty + i];
    } else {
        // x convert job: 1536 blocks, grid-stride over n8 = MROWS*EMB/8
        const int n8 = MROWS * EMB / 8;
        int idx    = (bid - 2304) * 256 + threadIdx.x;
        const int stride = 1536 * 256;
        for (int i = idx; i < n8; i += stride) {
            float4 a = ((const float4*)x)[i * 2];
            float4 b = ((const float4*)x)[i * 2 + 1];
            bf16x8 v;
            v[0] = (bf16_t)a.x; v[1] = (bf16_t)a.y; v[2] = (bf16_t)a.z; v[3] = (bf16_t)a.w;
            v[4] = (bf16_t)b.x; v[5] = (bf16_t)b.y; v[6] = (bf16_t)b.z; v[7] = (bf16_t)b.w;
            ((bf16x8*)xb)[i] = v;
        }
    }
}

// ---------------------------------------------------------------------------
// QKV GEMM (proven structure, 128x128 tile, BK=32, m97-style dbuf, XCD
// swizzle): C[M][N3] = A[M][768] * BT^T + bias. bf16 out; Q pre-scaled;
// V written transposed [bh][d][s].
// ---------------------------------------------------------------------------
template<int MODE>
__global__ __launch_bounds__(256) void gemm_kernel(
    const bf16_t* __restrict__ Av,
    const bf16_t* __restrict__ BT,
    const float* __restrict__ bias,
    float* __restrict__ out,
    bf16_t* __restrict__ qbuf,
    bf16_t* __restrict__ kbuf,
    bf16_t* __restrict__ vbuf,
    int Ncols)
{
    const int K = 768;
    __shared__ alignas(16) bf16_t As[2][128 * 32];
    __shared__ alignas(16) bf16_t Bs[2][128 * 32];

    const int tid    = threadIdx.x;
    const int wave   = tid >> 6;
    const int lane   = tid & 63;
    const int lane15 = lane & 15;
    const int quad   = lane >> 4;

    // bijective XCD swizzle: swz = (bid%8)*chunk + bid/8; chunk = grid/8.
    const int bid   = blockIdx.x;
    const int chunk = (int)(gridDim.x >> 3);
    const int swz   = (bid & 7) * chunk + (bid >> 3);
    const int NB    = Ncols >> 7;            // N-blocks (18)
    const int mBase = (swz / NB) * 128;
    const int nBase = (swz % NB) * 128;

    const int wm = (wave >> 1) * 64;
    const int wn = (wave & 1) * 64;

    f32x4 acc[4][4];
#pragma unroll
    for (int i = 0; i < 4; i++)
#pragma unroll
        for (int j = 0; j < 4; j++) acc[i][j] = (f32x4){0.f, 0.f, 0.f, 0.f};

    const bf16_t* aSrc = Av + (size_t)mBase * K;
    const bf16_t* bSrc = BT + (size_t)nBase * K;

    const int srow = lane >> 2;      // 0..15 within 16-row group
    const int sch  = lane & 3;       // physical chunk this lane fills

    auto issueA = [&](int k0, int buf) {
#pragma unroll
        for (int p = 0; p < 2; p++) {
            int r0  = p * 64 + wave * 16;
            int row = r0 + srow;
            int lch = sch ^ (row & 3);
            gld_lds16(&As[buf][r0 * 32], aSrc + (size_t)row * K + k0 + lch * 8);
        }
    };
    auto issueB = [&](int k0, int buf) {
#pragma unroll
        for (int p = 0; p < 2; p++) {
            int r0  = p * 64 + wave * 16;
            int row = r0 + srow;
            int lch = sch ^ (row & 3);
            gld_lds16(&Bs[buf][r0 * 32], bSrc + (size_t)row * K + k0 + lch * 8);
        }
    };

    issueA(0, 0);
    issueB(0, 0);

    for (int k0 = 0, it = 0; k0 < K; k0 += 32, it++) {
        const int buf = it & 1;
        __syncthreads();
        if (k0 + 32 < K) {
            issueB(k0 + 32, buf ^ 1);
            issueA(k0 + 32, buf ^ 1);
        }

        bf16x8 aF[4], bF[4];
#pragma unroll
        for (int t = 0; t < 4; t++) {
            int ra = wm + t * 16 + lane15;
            int rb = wn + t * 16 + lane15;
            aF[t] = *(const bf16x8*)&As[buf][ra * 32 + (quad ^ (ra & 3)) * 8];
            bF[t] = *(const bf16x8*)&Bs[buf][rb * 32 + (quad ^ (rb & 3)) * 8];
        }
#pragma unroll
        for (int i = 0; i < 4; i++)
#pragma unroll
            for (int j = 0; j < 4; j++)
                acc[i][j] = __builtin_amdgcn_mfma_f32_16x16x32_bf16(aF[i], bF[j], acc[i][j], 0, 0, 0);
    }

    const int region = nBase / EMB;          // wave-uniform (768%128==0)
#pragma unroll
    for (int i = 0; i < 4; i++) {
#pragma unroll
        for (int j = 0; j < 4; j++) {
            int gn = nBase + wn + j * 16 + lane15;
            float bv = bias[gn];
            if (region == 2) {
                // V: direct transposed write [bh][d][s]; 4 consecutive s -> 8 B store
                int within = gn - 2 * EMB;
                int h = within >> 6, d = within & 63;
                int gm0 = mBase + wm + i * 16 + quad * 4;
                int b = gm0 >> 11, s = gm0 & 2047;     // 128-tile never crosses batch
                int bh = b * NHEAD + h;
                bf16x4 v4;
#pragma unroll
                for (int r = 0; r < 4; r++) v4[r] = (bf16_t)(acc[i][j][r] + bv);
                *(bf16x4*)&vbuf[((size_t)bh * HDIM + d) * SEQ + s] = v4;
            } else {
                bf16_t* dst = (region == 0) ? qbuf : kbuf;
                const float scale = (region == 0) ? QSCALE : 1.0f;
                int within = gn - region * EMB;
                int h = within >> 6, d = within & 63;
#pragma unroll
                for (int r = 0; r < 4; r++) {
                    int gm = mBase + wm + i * 16 + quad * 4 + r;
                    int b = gm >> 11, s = gm & 2047;
                    int bh = b * NHEAD + h;
                    dst[((size_t)bh * SEQ + s) * HDIM + d] = (bf16_t)((acc[i][j][r] + bv) * scale);
                }
            }
        }
    }
}

// ---------------------------------------------------------------------------
// Proj GEMM — TM=64 x TN=128, BK=64, LDS 48 KB, 3 blocks/CU, XCD swizzle.
// ---------------------------------------------------------------------------
__global__ __launch_bounds__(256) void proj_kernel(
    const bf16_t* __restrict__ Av,    // [8192][768] bf16 (attn output)
    const bf16_t* __restrict__ BT,    // [768][768] bf16
    const float*  __restrict__ bias,
    float* __restrict__ out)          // [8192][768] fp32
{
    const int K = 768;
    __shared__ alignas(16) bf16_t As[2][64 * 64];     // 8 KB/buf
    __shared__ alignas(16) bf16_t Bs[2][128 * 64];    // 16 KB/buf

    const int tid    = threadIdx.x;
    const int wave   = tid >> 6;
    const int lane   = tid & 63;
    const int lane15 = lane & 15;
    const int quad   = lane >> 4;

    // bijective XCD swizzle: 768 blocks = 8 * 96.
    const int bid   = blockIdx.x;
    const int swz   = (bid & 7) * 96 + (bid >> 3);
    const int mBase = (swz / 6) * 64;
    const int nBase = (swz % 6) * 128;

    f32x4 acc[4][2];
#pragma unroll
    for (int t = 0; t < 4; t++)
#pragma unroll
        for (int u = 0; u < 2; u++) acc[t][u] = (f32x4){0.f, 0.f, 0.f, 0.f};

    const bf16_t* aSrc = Av + (size_t)mBase * K;
    const bf16_t* bSrc = BT + (size_t)nBase * K;

    const int srow8 = lane >> 3;   // row within 8-row issue
    const int sch8  = lane & 7;    // physical chunk this lane fills

    auto issueA = [&](int k0, int buf) {
#pragma unroll
        for (int p = 0; p < 2; p++) {
            int r0  = wave * 8 + p * 32;             // 4 waves x 2 = 64 rows
            int row = r0 + srow8;
            int lch = sch8 ^ (row & 7);
            gld_lds16(&As[buf][r0 * 64], aSrc + (size_t)row * K + k0 + lch * 8);
        }
    };
    auto issueB = [&](int k0, int buf) {
#pragma unroll
        for (int p = 0; p < 4; p++) {
            int r0  = wave * 8 + p * 32;             // 4 waves x 4 = 128 rows
            int row = r0 + srow8;
            int lch = sch8 ^ (row & 7);
            gld_lds16(&Bs[buf][r0 * 64], bSrc + (size_t)row * K + k0 + lch * 8);
        }
    };

    issueA(0, 0);
    issueB(0, 0);

    for (int k0 = 0, it = 0; k0 < K; k0 += 64, it++) {
        const int buf = it & 1;
        __syncthreads();
        if (k0 + 64 < K) {
            issueB(k0 + 64, buf ^ 1);
            issueA(k0 + 64, buf ^ 1);
        }

        bf16x8 aF[2][4], bF[2][2];
#pragma unroll
        for (int kk = 0; kk < 2; kk++) {
#pragma unroll
            for (int t = 0; t < 4; t++) {
                int ra = t * 16 + lane15;
                aF[kk][t] = *(const bf16x8*)&As[buf][ra * 64 + (((quad + kk * 4) ^ (ra & 7)) * 8)];
            }
#pragma unroll
            for (int u = 0; u < 2; u++) {
                int rb = wave * 32 + u * 16 + lane15;
                bF[kk][u] = *(const bf16x8*)&Bs[buf][rb * 64 + (((quad + kk * 4) ^ (rb & 7)) * 8)];
            }
        }
#pragma unroll
        for (int kk = 0; kk < 2; kk++)
#pragma unroll
            for (int t = 0; t < 4; t++)
#pragma unroll
                for (int u = 0; u < 2; u++)
                    acc[t][u] = __builtin_amdgcn_mfma_f32_16x16x32_bf16(aF[kk][t], bF[kk][u], acc[t][u], 0, 0, 0);
    }

#pragma unroll
    for (int t = 0; t < 4; t++) {
#pragma unroll
        for (int u = 0; u < 2; u++) {
            int gn = nBase + wave * 32 + u * 16 + lane15;
            float bv = bias[gn];
#pragma unroll
            for (int r = 0; r < 4; r++) {
                int gm = mBase + t * 16 + quad * 4 + r;
                out[(size_t)gm * EMB + gn] = acc[t][u][r] + bv;
            }
        }
    }
}

// ---------------------------------------------------------------------------
// Flash attention, causal — round 8: merged-pair {j,31-j} key loop (round-7
// balance + prefix-staging) with KVBLK=128 staged as TWO 64-key half-tiles
// per barrier round: barriers/block 24.5 -> ~12.7, prefetch depth 128 keys.
// K-fragments hoisted to registers once per half-tile, shared by both active
// q-sub-tiles (saves 8 ds_read_b128 on double-active iterations).
// LDS 73 KB -> 2 blocks/CU; 768 blocks = 3/CU uniform work.
// ---------------------------------------------------------------------------
__global__ __launch_bounds__(256) void attn_kernel(
    const bf16_t* __restrict__ qbuf,
    const bf16_t* __restrict__ kbuf,
    const bf16_t* __restrict__ vtbuf,
    bf16_t* __restrict__ obuf)
{
    __shared__ alignas(16) bf16_t Ks[2][2][64 * 64];  // [pairbuf][half][key][dim] 32 KB
    __shared__ alignas(16) bf16_t Vs[2][2][64 * 64];  // [pairbuf][half][dim][key] 32 KB
    __shared__ alignas(16) bf16_t Plds[4][16 * 72];   // per-wave O-transpose scratch 9 KB

    const int tid    = threadIdx.x;
    const int wave   = tid >> 6;
    const int lane   = tid & 63;
    const int lane15 = lane & 15;
    const int quad   = lane >> 4;

    // bijective XCD swizzle: 768 blocks = 8 * 96.
    const int bid = blockIdx.x;
    const int swz = (bid & 7) * 96 + (bid >> 3);
    const int bh = swz >> 4;
    const int j  = swz & 15;

    const bf16_t* Qp = qbuf  + (size_t)bh * SEQ * HDIM;
    const bf16_t* Kp = kbuf  + (size_t)bh * SEQ * HDIM;
    const bf16_t* Vp = vtbuf + (size_t)bh * HDIM * SEQ;
    bf16_t* pl = &Plds[wave][0];
    const int b = bh / NHEAD, h = bh % NHEAD;

    const int srow8 = lane >> 3;   // 0..7 within 8-row group
    const int sch8  = lane & 7;    // physical chunk this lane fills

    // stage one 128-key pair (two 64-key half-tiles, same layout/swizzle each)
    auto issueKV = [&](int kbp, int buf) {
#pragma unroll
        for (int hh = 0; hh < 2; hh++) {
            const int kb = kbp + hh * 64;
#pragma unroll
            for (int p = 0; p < 2; p++) {
                int r0  = p * 32 + wave * 8;             // wave-uniform
                int row = r0 + srow8;
                int lch = sch8 ^ (row & 7);              // logical chunk to fetch
                gld_lds16(&Ks[buf][hh][r0 * 64], Kp + (size_t)(kb + row) * HDIM + lch * 8);
                gld_lds16(&Vs[buf][hh][r0 * 64], Vp + (size_t)row * SEQ + kb + lch * 8);
            }
        }
    };

    // sub-tile 0: q-tile j (keys kt<=j); sub-tile 1: q-tile 31-j (all kt)
    const int q0s[2] = { j * 64 + wave * 16, (31 - j) * 64 + wave * 16 };

    bf16x8 qf[2][2];
#pragma unroll
    for (int qq = 0; qq < 2; qq++) {
        qf[qq][0] = *(const bf16x8*)&Qp[(size_t)(q0s[qq] + lane15) * HDIM + quad * 8];
        qf[qq][1] = *(const bf16x8*)&Qp[(size_t)(q0s[qq] + lane15) * HDIM + 32 + quad * 8];
    }

    float lrow[2] = {0.f, 0.f};
    f32x4 oT[2][4];
#pragma unroll
    for (int qq = 0; qq < 2; qq++)
#pragma unroll
        for (int t = 0; t < 4; t++) oT[qq][t] = (f32x4){0.f, 0.f, 0.f, 0.f};

    const int nT = 32 - j;                   // 64-key tiles for B's full range
    const int nP = (nT + 1) >> 1;            // 128-key pair rounds
    issueKV(0, 0);

    for (int ktp = 0; ktp < nP; ktp++) {
        const int buf = ktp & 1;
        __syncthreads();                                     // pair ktp ready
        if (ktp + 1 < nP) issueKV((ktp + 1) * 128, buf ^ 1); // prefetch next pair

#pragma unroll
        for (int half = 0; half < 2; half++) {
            const int kt = ktp * 2 + half;
            if (kt >= nT) continue;          // odd-tail (wave-uniform)
            const int kb = kt * 64;

            // hoist K fragments once; shared by both q-sub-tiles
            bf16x8 kf[4][2];
#pragma unroll
            for (int kg = 0; kg < 4; kg++) {
                int row = kg * 16 + lane15;
                kf[kg][0] = *(const bf16x8*)&Ks[buf][half][row * 64 + ((quad    ) ^ (row & 7)) * 8];
                kf[kg][1] = *(const bf16x8*)&Ks[buf][half][row * 64 + ((quad + 4) ^ (row & 7)) * 8];
            }

#pragma unroll
            for (int qq = 0; qq < 2; qq++) {
                const int q0q = q0s[qq];
                if (qq == 0 && kt > j) continue;   // A done (wave-uniform)

                // QK^T -> S^T[key][query]: A = K fragment, B = Q fragment
                f32x4 sT[4];
                __builtin_amdgcn_s_setprio(1);
#pragma unroll
                for (int kg = 0; kg < 4; kg++) {
                    sT[kg] = (f32x4){0.f, 0.f, 0.f, 0.f};
                    sT[kg] = __builtin_amdgcn_mfma_f32_16x16x32_bf16(kf[kg][0], qf[qq][0], sT[kg], 0, 0, 0);
                    sT[kg] = __builtin_amdgcn_mfma_f32_16x16x32_bf16(kf[kg][1], qf[qq][1], sT[kg], 0, 0, 0);
                }
                __builtin_amdgcn_s_setprio(0);

                // causal mask: only the diagonal tile (wave-uniform test)
                if (kb + 64 > q0q) {
                    const int query = q0q + lane15;
#pragma unroll
                    for (int kg = 0; kg < 4; kg++) {
                        int key0 = kb + kg * 16 + quad * 4;
#pragma unroll
                        for (int r = 0; r < 4; r++)
                            sT[kg][r] = (key0 + r <= query) ? sT[kg][r] : -1e30f;
                    }
                }

                // unnormalized softmax: P^T = exp2(S^T); l += sum; pack to bf16
                bf16x4 pf[4];
#pragma unroll
                for (int kg = 0; kg < 4; kg++) {
#pragma unroll
                    for (int r = 0; r < 4; r++) sT[kg][r] = fast_exp2(sT[kg][r]);
                    lrow[qq] += (sT[kg][0] + sT[kg][1]) + (sT[kg][2] + sT[kg][3]);
                    bf16x4 v;
#pragma unroll
                    for (int r = 0; r < 4; r++) v[r] = (bf16_t)sT[kg][r];
                    pf[kg] = v;
                }

                // PV: O^T[d][q] += V^T[d][k] * P^T[k][q], 16x16x16 MFMAs.
                __builtin_amdgcn_s_setprio(1);
#pragma unroll
                for (int t = 0; t < 4; t++) {
                    int vrow = t * 16 + lane15;
#pragma unroll
                    for (int kg = 0; kg < 4; kg++) {
                        int c    = kg * 2 + (quad >> 1);           // logical 8-elem chunk
                        int phys = c ^ (vrow & 7);
                        bf16x4 vf = *(const bf16x4*)&Vs[buf][half][vrow * 64 + phys * 8 + (quad & 1) * 4];
                        oT[qq][t] = mfma16_bf16(vf, pf[kg], oT[qq][t]);
                    }
                }
                __builtin_amdgcn_s_setprio(0);
            }
        }
    }

    // epilogue per sub-tile: l-reduce, O^T -> LDS -> coalesced global write
#pragma unroll
    for (int qq = 0; qq < 2; qq++) {
        const int q0q = q0s[qq];
        float l = lrow[qq];
        l += __shfl_xor(l, 16, 64);
        l += __shfl_xor(l, 32, 64);
        const float inv = 1.0f / l;

#pragma unroll
        for (int t = 0; t < 4; t++)
#pragma unroll
            for (int r = 0; r < 4; r++)
                pl[lane15 * 72 + t * 16 + quad * 4 + r] = (bf16_t)(oT[qq][t][r] * inv);

        const int qrow = lane >> 2;      // 0..15 query within sub-tile
        const int ch   = lane & 3;       // 8-elem d-chunk
        bf16_t* orow = &obuf[((size_t)(b * SEQ + q0q + qrow)) * EMB + h * HDIM];
#pragma unroll
        for (int p = 0; p < 2; p++) {
            bf16x8 v = *(const bf16x8*)&pl[qrow * 72 + (ch + p * 4) * 8];
            *(bf16x8*)&orow[(ch + p * 4) * 8] = v;
        }
    }
}

// ---------------------------------------------------------------------------
extern "C" void kernel_launch(void* const* d_in, const int* in_sizes, int n_in,
                              void* d_out, int out_size, void* d_ws, size_t ws_size,
                              hipStream_t stream) {
    const float* x      = (const float*)d_in[0];
    // d_in[1] = mask: causal by construction, implemented analytically
    const float* W_attn = (const float*)d_in[2];
    const float* b_attn = (const float*)d_in[3];
    const float* W_proj = (const float*)d_in[4];
    const float* b_proj = (const float*)d_in[5];
    float* out = (float*)d_out;   // fp32 output

    bf16_t* ws  = (bf16_t*)d_ws;
    bf16_t* WaT = ws;                                         // [2304][768]
    bf16_t* WpT = WaT + (size_t)N3 * EMB;                     // [768][768]
    bf16_t* Qb  = WpT + (size_t)EMB * EMB;                    // [B*H][S][D]
    bf16_t* Kb  = Qb + (size_t)BATCH * NHEAD * SEQ * HDIM;
    bf16_t* Vt  = Kb + (size_t)BATCH * NHEAD * SEQ * HDIM;    // [B*H][D][S]
    bf16_t* Ob  = Vt + (size_t)BATCH * NHEAD * SEQ * HDIM;    // [8192][768]
    bf16_t* xb  = Ob;   // alias: bf16 x is dead before attn writes Ob

    // one prep launch: both W transposes + x convert
    prep_kernel<<<3840, 256, 0, stream>>>(W_attn, WaT, W_proj, WpT, x, xb);

    // QKV: 1152 blocks (64 M x 18 N), XCD-swizzled inside the kernel.
    gemm_kernel<1><<<1152, 256, 0, stream>>>(
        xb, WaT, b_attn, nullptr, Qb, Kb, Vt, N3);

    // attn: 768 blocks = (bh, pair {j,31-j}), paired 128-key staging rounds.
    attn_kernel<<<768, 256, 0, stream>>>(Qb, Kb, Vt, Ob);

    // proj: 768 blocks (128 M x 6 N), TM=64 x TN=128, BK=64, XCD-swizzled.
    proj_kernel<<<768, 256, 0, stream>>>(Ob, WpT, b_proj, out);
}

// Round 9
// 217.980 us; speedup vs baseline: 1.0533x; 1.0533x over previous
//
#include <hip/hip_runtime.h>
#include <stdint.h>

// Problem constants
#define NHEAD 12
#define HDIM  64
#define EMB   768
#define N3    2304      // 3*EMB
#define SEQ   2048
#define BATCH 4
#define MROWS 8192      // BATCH*SEQ

// 0.125 * log2(e): folds the 1/sqrt(64) scale AND the e->2 base change into Q.
#define QSCALE 0.18033688011112042f

typedef __bf16 bf16_t;
typedef __bf16 bf16x8 __attribute__((ext_vector_type(8)));
typedef __bf16 bf16x4 __attribute__((ext_vector_type(4)));
typedef short  s16x4  __attribute__((ext_vector_type(4)));
typedef float  f32x4  __attribute__((ext_vector_type(4)));

// async global->LDS, 16 B/lane. HW scatters lane i to (readfirstlane(lds)) + i*16.
__device__ __forceinline__ void gld_lds16(void* lds, const void* g) {
    __builtin_amdgcn_global_load_lds((const __attribute__((address_space(1))) void*)g,
                                     (__attribute__((address_space(3))) void*)lds,
                                     16, 0, 0);
}

// raw v_exp_f32 (2^x): args are provably in-range; skips libm denormal fixup.
__device__ __forceinline__ float fast_exp2(float x) {
    return __builtin_amdgcn_exp2f(x);
}

// 16x16x16 bf16 MFMA (K=16): A 2 VGPR / B 2 VGPR / C-D 4 (cdna4_isa §10).
__device__ __forceinline__ f32x4 mfma16_bf16(bf16x4 a, bf16x4 b, f32x4 c) {
#if __has_builtin(__builtin_amdgcn_mfma_f32_16x16x16_bf16)
    return __builtin_amdgcn_mfma_f32_16x16x16_bf16(a, b, c, 0, 0, 0);
#else
    union U { bf16x4 h; s16x4 s; };
    U ua, ub; ua.h = a; ub.h = b;
    return __builtin_amdgcn_mfma_f32_16x16x16bf16_1k(ua.s, ub.s, c, 0, 0, 0);
#endif
}

// ---------------------------------------------------------------------------
// Fused prep: one launch does
//   blocks [0,1728)    : W_attn [768][2304] -> WaT [2304][768] bf16 (32x32 tiles)
//   blocks [1728,2304) : W_proj [768][768]  -> WpT [768][768]  bf16
//   blocks [2304,3840) : x fp32 -> bf16 streaming convert
// ---------------------------------------------------------------------------
__global__ __launch_bounds__(256) void prep_kernel(
    const float* __restrict__ Wa, bf16_t* __restrict__ WaT,
    const float* __restrict__ Wp, bf16_t* __restrict__ WpT,
    const float* __restrict__ x,  bf16_t* __restrict__ xb)
{
    __shared__ float tile[32][33];
    const int bid = blockIdx.x;
    if (bid < 2304) {
        // transpose+convert job
        const float* W; bf16_t* WT; int K, N, b;
        if (bid < 1728) { W = Wa; WT = WaT; K = 768; N = 2304; b = bid; }
        else            { W = Wp; WT = WpT; K = 768; N = 768;  b = bid - 1728; }
        const int nb = N / 32;
        const int n0 = (b % nb) * 32, k0 = (b / nb) * 32;
        const int tx = threadIdx.x & 31, ty = threadIdx.x >> 5;   // ty 0..7
#pragma unroll
        for (int i = 0; i < 32; i += 8)
            tile[ty + i][tx] = W[(size_t)(k0 + ty + i) * N + (n0 + tx)];
        __syncthreads();
#pragma unroll
        for (int i = 0; i < 32; i += 8)
            WT[(size_t)(n0 + ty + i) * K + (k0 + tx)] = (bf16_t)tile[tx][ty + i];
    } else {
        // x convert job: 1536 blocks, grid-stride over n8 = MROWS*EMB/8
        const int n8 = MROWS * EMB / 8;
        int idx    = (bid - 2304) * 256 + threadIdx.x;
        const int stride = 1536 * 256;
        for (int i = idx; i < n8; i += stride) {
            float4 a = ((const float4*)x)[i * 2];
            float4 b = ((const float4*)x)[i * 2 + 1];
            bf16x8 v;
            v[0] = (bf16_t)a.x; v[1] = (bf16_t)a.y; v[2] = (bf16_t)a.z; v[3] = (bf16_t)a.w;
            v[4] = (bf16_t)b.x; v[5] = (bf16_t)b.y; v[6] = (bf16_t)b.z; v[7] = (bf16_t)b.w;
            ((bf16x8*)xb)[i] = v;
        }
    }
}

// ---------------------------------------------------------------------------
// QKV GEMM (proven structure, 128x128 tile, BK=32, m97-style dbuf, XCD
// swizzle): C[M][N3] = A[M][768] * BT^T + bias. bf16 out; Q pre-scaled;
// V written transposed [bh][d][s].
// ---------------------------------------------------------------------------
template<int MODE>
__global__ __launch_bounds__(256) void gemm_kernel(
    const bf16_t* __restrict__ Av,
    const bf16_t* __restrict__ BT,
    const float* __restrict__ bias,
    float* __restrict__ out,
    bf16_t* __restrict__ qbuf,
    bf16_t* __restrict__ kbuf,
    bf16_t* __restrict__ vbuf,
    int Ncols)
{
    const int K = 768;
    __shared__ alignas(16) bf16_t As[2][128 * 32];
    __shared__ alignas(16) bf16_t Bs[2][128 * 32];

    const int tid    = threadIdx.x;
    const int wave   = tid >> 6;
    const int lane   = tid & 63;
    const int lane15 = lane & 15;
    const int quad   = lane >> 4;

    // bijective XCD swizzle: swz = (bid%8)*chunk + bid/8; chunk = grid/8.
    const int bid   = blockIdx.x;
    const int chunk = (int)(gridDim.x >> 3);
    const int swz   = (bid & 7) * chunk + (bid >> 3);
    const int NB    = Ncols >> 7;            // N-blocks (18)
    const int mBase = (swz / NB) * 128;
    const int nBase = (swz % NB) * 128;

    const int wm = (wave >> 1) * 64;
    const int wn = (wave & 1) * 64;

    f32x4 acc[4][4];
#pragma unroll
    for (int i = 0; i < 4; i++)
#pragma unroll
        for (int j = 0; j < 4; j++) acc[i][j] = (f32x4){0.f, 0.f, 0.f, 0.f};

    const bf16_t* aSrc = Av + (size_t)mBase * K;
    const bf16_t* bSrc = BT + (size_t)nBase * K;

    const int srow = lane >> 2;      // 0..15 within 16-row group
    const int sch  = lane & 3;       // physical chunk this lane fills

    auto issueA = [&](int k0, int buf) {
#pragma unroll
        for (int p = 0; p < 2; p++) {
            int r0  = p * 64 + wave * 16;
            int row = r0 + srow;
            int lch = sch ^ (row & 3);
            gld_lds16(&As[buf][r0 * 32], aSrc + (size_t)row * K + k0 + lch * 8);
        }
    };
    auto issueB = [&](int k0, int buf) {
#pragma unroll
        for (int p = 0; p < 2; p++) {
            int r0  = p * 64 + wave * 16;
            int row = r0 + srow;
            int lch = sch ^ (row & 3);
            gld_lds16(&Bs[buf][r0 * 32], bSrc + (size_t)row * K + k0 + lch * 8);
        }
    };

    issueA(0, 0);
    issueB(0, 0);

    for (int k0 = 0, it = 0; k0 < K; k0 += 32, it++) {
        const int buf = it & 1;
        __syncthreads();
        if (k0 + 32 < K) {
            issueB(k0 + 32, buf ^ 1);
            issueA(k0 + 32, buf ^ 1);
        }

        bf16x8 aF[4], bF[4];
#pragma unroll
        for (int t = 0; t < 4; t++) {
            int ra = wm + t * 16 + lane15;
            int rb = wn + t * 16 + lane15;
            aF[t] = *(const bf16x8*)&As[buf][ra * 32 + (quad ^ (ra & 3)) * 8];
            bF[t] = *(const bf16x8*)&Bs[buf][rb * 32 + (quad ^ (rb & 3)) * 8];
        }
#pragma unroll
        for (int i = 0; i < 4; i++)
#pragma unroll
            for (int j = 0; j < 4; j++)
                acc[i][j] = __builtin_amdgcn_mfma_f32_16x16x32_bf16(aF[i], bF[j], acc[i][j], 0, 0, 0);
    }

    const int region = nBase / EMB;          // wave-uniform (768%128==0)
#pragma unroll
    for (int i = 0; i < 4; i++) {
#pragma unroll
        for (int j = 0; j < 4; j++) {
            int gn = nBase + wn + j * 16 + lane15;
            float bv = bias[gn];
            if (region == 2) {
                // V: direct transposed write [bh][d][s]; 4 consecutive s -> 8 B store
                int within = gn - 2 * EMB;
                int h = within >> 6, d = within & 63;
                int gm0 = mBase + wm + i * 16 + quad * 4;
                int b = gm0 >> 11, s = gm0 & 2047;     // 128-tile never crosses batch
                int bh = b * NHEAD + h;
                bf16x4 v4;
#pragma unroll
                for (int r = 0; r < 4; r++) v4[r] = (bf16_t)(acc[i][j][r] + bv);
                *(bf16x4*)&vbuf[((size_t)bh * HDIM + d) * SEQ + s] = v4;
            } else {
                bf16_t* dst = (region == 0) ? qbuf : kbuf;
                const float scale = (region == 0) ? QSCALE : 1.0f;
                int within = gn - region * EMB;
                int h = within >> 6, d = within & 63;
#pragma unroll
                for (int r = 0; r < 4; r++) {
                    int gm = mBase + wm + i * 16 + quad * 4 + r;
                    int b = gm >> 11, s = gm & 2047;
                    int bh = b * NHEAD + h;
                    dst[((size_t)bh * SEQ + s) * HDIM + d] = (bf16_t)((acc[i][j][r] + bv) * scale);
                }
            }
        }
    }
}

// ---------------------------------------------------------------------------
// Proj GEMM — TM=64 x TN=128, BK=64, LDS 48 KB, 3 blocks/CU, XCD swizzle.
// ---------------------------------------------------------------------------
__global__ __launch_bounds__(256) void proj_kernel(
    const bf16_t* __restrict__ Av,    // [8192][768] bf16 (attn output)
    const bf16_t* __restrict__ BT,    // [768][768] bf16
    const float*  __restrict__ bias,
    float* __restrict__ out)          // [8192][768] fp32
{
    const int K = 768;
    __shared__ alignas(16) bf16_t As[2][64 * 64];     // 8 KB/buf
    __shared__ alignas(16) bf16_t Bs[2][128 * 64];    // 16 KB/buf

    const int tid    = threadIdx.x;
    const int wave   = tid >> 6;
    const int lane   = tid & 63;
    const int lane15 = lane & 15;
    const int quad   = lane >> 4;

    // bijective XCD swizzle: 768 blocks = 8 * 96.
    const int bid   = blockIdx.x;
    const int swz   = (bid & 7) * 96 + (bid >> 3);
    const int mBase = (swz / 6) * 64;
    const int nBase = (swz % 6) * 128;

    f32x4 acc[4][2];
#pragma unroll
    for (int t = 0; t < 4; t++)
#pragma unroll
        for (int u = 0; u < 2; u++) acc[t][u] = (f32x4){0.f, 0.f, 0.f, 0.f};

    const bf16_t* aSrc = Av + (size_t)mBase * K;
    const bf16_t* bSrc = BT + (size_t)nBase * K;

    const int srow8 = lane >> 3;   // row within 8-row issue
    const int sch8  = lane & 7;    // physical chunk this lane fills

    auto issueA = [&](int k0, int buf) {
#pragma unroll
        for (int p = 0; p < 2; p++) {
            int r0  = wave * 8 + p * 32;             // 4 waves x 2 = 64 rows
            int row = r0 + srow8;
            int lch = sch8 ^ (row & 7);
            gld_lds16(&As[buf][r0 * 64], aSrc + (size_t)row * K + k0 + lch * 8);
        }
    };
    auto issueB = [&](int k0, int buf) {
#pragma unroll
        for (int p = 0; p < 4; p++) {
            int r0  = wave * 8 + p * 32;             // 4 waves x 4 = 128 rows
            int row = r0 + srow8;
            int lch = sch8 ^ (row & 7);
            gld_lds16(&Bs[buf][r0 * 64], bSrc + (size_t)row * K + k0 + lch * 8);
        }
    };

    issueA(0, 0);
    issueB(0, 0);

    for (int k0 = 0, it = 0; k0 < K; k0 += 64, it++) {
        const int buf = it & 1;
        __syncthreads();
        if (k0 + 64 < K) {
            issueB(k0 + 64, buf ^ 1);
            issueA(k0 + 64, buf ^ 1);
        }

        bf16x8 aF[2][4], bF[2][2];
#pragma unroll
        for (int kk = 0; kk < 2; kk++) {
#pragma unroll
            for (int t = 0; t < 4; t++) {
                int ra = t * 16 + lane15;
                aF[kk][t] = *(const bf16x8*)&As[buf][ra * 64 + (((quad + kk * 4) ^ (ra & 7)) * 8)];
            }
#pragma unroll
            for (int u = 0; u < 2; u++) {
                int rb = wave * 32 + u * 16 + lane15;
                bF[kk][u] = *(const bf16x8*)&Bs[buf][rb * 64 + (((quad + kk * 4) ^ (rb & 7)) * 8)];
            }
        }
#pragma unroll
        for (int kk = 0; kk < 2; kk++)
#pragma unroll
            for (int t = 0; t < 4; t++)
#pragma unroll
                for (int u = 0; u < 2; u++)
                    acc[t][u] = __builtin_amdgcn_mfma_f32_16x16x32_bf16(aF[kk][t], bF[kk][u], acc[t][u], 0, 0, 0);
    }

#pragma unroll
    for (int t = 0; t < 4; t++) {
#pragma unroll
        for (int u = 0; u < 2; u++) {
            int gn = nBase + wave * 32 + u * 16 + lane15;
            float bv = bias[gn];
#pragma unroll
            for (int r = 0; r < 4; r++) {
                int gm = mBase + t * 16 + quad * 4 + r;
                out[(size_t)gm * EMB + gn] = acc[t][u][r] + bv;
            }
        }
    }
}

// ---------------------------------------------------------------------------
// Flash attention, causal — round 9: REVERT to round-7 geometry (KVBLK=64,
// LDS 41 KB, 3 blocks/CU — round-8's KVBLK=128 cut occupancy to 2/CU and
// regressed) + keep round-8's orthogonal K-fragment hoist: kf[] loaded once
// per key-tile, shared by both active q-sub-tiles (saves 8 ds_read_b128 on
// double-active iterations; occupancy-neutral at ~108 VGPR).
// Merged-pair {j,31-j} key loop: uniform 33 compute-quanta/block, stagings
// 32-j (avg 24.5). XCD swizzle 768 = 8 x 96.
// ---------------------------------------------------------------------------
__global__ __launch_bounds__(256) void attn_kernel(
    const bf16_t* __restrict__ qbuf,
    const bf16_t* __restrict__ kbuf,
    const bf16_t* __restrict__ vtbuf,
    bf16_t* __restrict__ obuf)
{
    __shared__ alignas(16) bf16_t Ks[2][64 * 64];     // [key][dim], dbuf 16 KB
    __shared__ alignas(16) bf16_t Vs[2][64 * 64];     // [dim][key], dbuf 16 KB
    __shared__ alignas(16) bf16_t Plds[4][16 * 72];   // per-wave O-transpose scratch

    const int tid    = threadIdx.x;
    const int wave   = tid >> 6;
    const int lane   = tid & 63;
    const int lane15 = lane & 15;
    const int quad   = lane >> 4;

    // bijective XCD swizzle: 768 blocks = 8 * 96.
    const int bid = blockIdx.x;
    const int swz = (bid & 7) * 96 + (bid >> 3);
    const int bh = swz >> 4;
    const int j  = swz & 15;

    const bf16_t* Qp = qbuf  + (size_t)bh * SEQ * HDIM;
    const bf16_t* Kp = kbuf  + (size_t)bh * SEQ * HDIM;
    const bf16_t* Vp = vtbuf + (size_t)bh * HDIM * SEQ;
    bf16_t* pl = &Plds[wave][0];
    const int b = bh / NHEAD, h = bh % NHEAD;

    const int srow8 = lane >> 3;   // 0..7 within 8-row group
    const int sch8  = lane & 7;    // physical chunk this lane fills

    auto issueKV = [&](int kb, int buf) {
#pragma unroll
        for (int p = 0; p < 2; p++) {
            int r0  = p * 32 + wave * 8;             // wave-uniform
            int row = r0 + srow8;
            int lch = sch8 ^ (row & 7);              // logical chunk to fetch
            gld_lds16(&Ks[buf][r0 * 64], Kp + (size_t)(kb + row) * HDIM + lch * 8);
            gld_lds16(&Vs[buf][r0 * 64], Vp + (size_t)row * SEQ + kb + lch * 8);
        }
    };

    // sub-tile 0: q-tile j (keys kt<=j); sub-tile 1: q-tile 31-j (all kt)
    const int q0s[2] = { j * 64 + wave * 16, (31 - j) * 64 + wave * 16 };

    bf16x8 qf[2][2];
#pragma unroll
    for (int qq = 0; qq < 2; qq++) {
        qf[qq][0] = *(const bf16x8*)&Qp[(size_t)(q0s[qq] + lane15) * HDIM + quad * 8];
        qf[qq][1] = *(const bf16x8*)&Qp[(size_t)(q0s[qq] + lane15) * HDIM + 32 + quad * 8];
    }

    float lrow[2] = {0.f, 0.f};
    f32x4 oT[2][4];
#pragma unroll
    for (int qq = 0; qq < 2; qq++)
#pragma unroll
        for (int t = 0; t < 4; t++) oT[qq][t] = (f32x4){0.f, 0.f, 0.f, 0.f};

    const int nT = 32 - j;                   // stagings: B's full key range
    issueKV(0, 0);

    for (int kt = 0; kt < nT; kt++) {
        const int buf = kt & 1;
        __syncthreads();                                   // tile kt ready
        if (kt + 1 < nT) issueKV((kt + 1) * 64, buf ^ 1);  // prefetch

        const int kb = kt * 64;

        // hoist K fragments once per tile; shared by both q-sub-tiles
        bf16x8 kf[4][2];
#pragma unroll
        for (int kg = 0; kg < 4; kg++) {
            int row = kg * 16 + lane15;
            kf[kg][0] = *(const bf16x8*)&Ks[buf][row * 64 + ((quad    ) ^ (row & 7)) * 8];
            kf[kg][1] = *(const bf16x8*)&Ks[buf][row * 64 + ((quad + 4) ^ (row & 7)) * 8];
        }

#pragma unroll
        for (int qq = 0; qq < 2; qq++) {
            const int q0q = q0s[qq];
            if (qq == 0 && kt > j) continue;   // A done (wave-uniform branch)

            // QK^T -> S^T[key][query]: A = K fragment, B = Q fragment
            f32x4 sT[4];
            __builtin_amdgcn_s_setprio(1);
#pragma unroll
            for (int kg = 0; kg < 4; kg++) {
                sT[kg] = (f32x4){0.f, 0.f, 0.f, 0.f};
                sT[kg] = __builtin_amdgcn_mfma_f32_16x16x32_bf16(kf[kg][0], qf[qq][0], sT[kg], 0, 0, 0);
                sT[kg] = __builtin_amdgcn_mfma_f32_16x16x32_bf16(kf[kg][1], qf[qq][1], sT[kg], 0, 0, 0);
            }
            __builtin_amdgcn_s_setprio(0);

            // causal mask: only the diagonal tile (wave-uniform test)
            if (kb + 64 > q0q) {
                const int query = q0q + lane15;
#pragma unroll
                for (int kg = 0; kg < 4; kg++) {
                    int key0 = kb + kg * 16 + quad * 4;
#pragma unroll
                    for (int r = 0; r < 4; r++)
                        sT[kg][r] = (key0 + r <= query) ? sT[kg][r] : -1e30f;
                }
            }

            // unnormalized softmax: P^T = exp2(S^T); l += sum; pack to bf16
            bf16x4 pf[4];
#pragma unroll
            for (int kg = 0; kg < 4; kg++) {
#pragma unroll
                for (int r = 0; r < 4; r++) sT[kg][r] = fast_exp2(sT[kg][r]);
                lrow[qq] += (sT[kg][0] + sT[kg][1]) + (sT[kg][2] + sT[kg][3]);
                bf16x4 v;
#pragma unroll
                for (int r = 0; r < 4; r++) v[r] = (bf16_t)sT[kg][r];
                pf[kg] = v;
            }

            // PV: O^T[d][q] += V^T[d][k] * P^T[k][q], 16x16x16 MFMAs.
            __builtin_amdgcn_s_setprio(1);
#pragma unroll
            for (int t = 0; t < 4; t++) {
                int vrow = t * 16 + lane15;
#pragma unroll
                for (int kg = 0; kg < 4; kg++) {
                    int c    = kg * 2 + (quad >> 1);           // logical 8-elem chunk
                    int phys = c ^ (vrow & 7);
                    bf16x4 vf = *(const bf16x4*)&Vs[buf][vrow * 64 + phys * 8 + (quad & 1) * 4];
                    oT[qq][t] = mfma16_bf16(vf, pf[kg], oT[qq][t]);
                }
            }
            __builtin_amdgcn_s_setprio(0);
        }
    }

    // epilogue per sub-tile: l-reduce, O^T -> LDS -> coalesced global write
#pragma unroll
    for (int qq = 0; qq < 2; qq++) {
        const int q0q = q0s[qq];
        float l = lrow[qq];
        l += __shfl_xor(l, 16, 64);
        l += __shfl_xor(l, 32, 64);
        const float inv = 1.0f / l;

#pragma unroll
        for (int t = 0; t < 4; t++)
#pragma unroll
            for (int r = 0; r < 4; r++)
                pl[lane15 * 72 + t * 16 + quad * 4 + r] = (bf16_t)(oT[qq][t][r] * inv);

        const int qrow = lane >> 2;      // 0..15 query within sub-tile
        const int ch   = lane & 3;       // 8-elem d-chunk
        bf16_t* orow = &obuf[((size_t)(b * SEQ + q0q + qrow)) * EMB + h * HDIM];
#pragma unroll
        for (int p = 0; p < 2; p++) {
            bf16x8 v = *(const bf16x8*)&pl[qrow * 72 + (ch + p * 4) * 8];
            *(bf16x8*)&orow[(ch + p * 4) * 8] = v;
        }
    }
}

// ---------------------------------------------------------------------------
extern "C" void kernel_launch(void* const* d_in, const int* in_sizes, int n_in,
                              void* d_out, int out_size, void* d_ws, size_t ws_size,
                              hipStream_t stream) {
    const float* x      = (const float*)d_in[0];
    // d_in[1] = mask: causal by construction, implemented analytically
    const float* W_attn = (const float*)d_in[2];
    const float* b_attn = (const float*)d_in[3];
    const float* W_proj = (const float*)d_in[4];
    const float* b_proj = (const float*)d_in[5];
    float* out = (float*)d_out;   // fp32 output

    bf16_t* ws  = (bf16_t*)d_ws;
    bf16_t* WaT = ws;                                         // [2304][768]
    bf16_t* WpT = WaT + (size_t)N3 * EMB;                     // [768][768]
    bf16_t* Qb  = WpT + (size_t)EMB * EMB;                    // [B*H][S][D]
    bf16_t* Kb  = Qb + (size_t)BATCH * NHEAD * SEQ * HDIM;
    bf16_t* Vt  = Kb + (size_t)BATCH * NHEAD * SEQ * HDIM;    // [B*H][D][S]
    bf16_t* Ob  = Vt + (size_t)BATCH * NHEAD * SEQ * HDIM;    // [8192][768]
    bf16_t* xb  = Ob;   // alias: bf16 x is dead before attn writes Ob

    // one prep launch: both W transposes + x convert
    prep_kernel<<<3840, 256, 0, stream>>>(W_attn, WaT, W_proj, WpT, x, xb);

    // QKV: 1152 blocks (64 M x 18 N), XCD-swizzled inside the kernel.
    gemm_kernel<1><<<1152, 256, 0, stream>>>(
        xb, WaT, b_attn, nullptr, Qb, Kb, Vt, N3);

    // attn: 768 blocks = (bh, pair {j,31-j}), merged key loop, uniform work.
    attn_kernel<<<768, 256, 0, stream>>>(Qb, Kb, Vt, Ob);

    // proj: 768 blocks (128 M x 6 N), TM=64 x TN=128, BK=64, XCD-swizzled.
    proj_kernel<<<768, 256, 0, stream>>>(Ob, WpT, b_proj, out);
}

// Round 10
// 217.054 us; speedup vs baseline: 1.0577x; 1.0043x over previous
//
#include <hip/hip_runtime.h>
#include <stdint.h>

// Problem constants
#define NHEAD 12
#define HDIM  64
#define EMB   768
#define N3    2304      // 3*EMB
#define SEQ   2048
#define BATCH 4
#define MROWS 8192      // BATCH*SEQ

// 0.125 * log2(e): folds the 1/sqrt(64) scale AND the e->2 base change into Q.
#define QSCALE 0.18033688011112042f

typedef __bf16 bf16_t;
typedef __bf16 bf16x8 __attribute__((ext_vector_type(8)));
typedef __bf16 bf16x4 __attribute__((ext_vector_type(4)));
typedef short  s16x4  __attribute__((ext_vector_type(4)));
typedef float  f32x4  __attribute__((ext_vector_type(4)));

// async global->LDS, 16 B/lane. HW scatters lane i to (readfirstlane(lds)) + i*16.
__device__ __forceinline__ void gld_lds16(void* lds, const void* g) {
    __builtin_amdgcn_global_load_lds((const __attribute__((address_space(1))) void*)g,
                                     (__attribute__((address_space(3))) void*)lds,
                                     16, 0, 0);
}

// raw v_exp_f32 (2^x): args are provably in-range; skips libm denormal fixup.
__device__ __forceinline__ float fast_exp2(float x) {
    return __builtin_amdgcn_exp2f(x);
}

// 16x16x16 bf16 MFMA (K=16): A 2 VGPR / B 2 VGPR / C-D 4 (cdna4_isa §10).
__device__ __forceinline__ f32x4 mfma16_bf16(bf16x4 a, bf16x4 b, f32x4 c) {
#if __has_builtin(__builtin_amdgcn_mfma_f32_16x16x16_bf16)
    return __builtin_amdgcn_mfma_f32_16x16x16_bf16(a, b, c, 0, 0, 0);
#else
    union U { bf16x4 h; s16x4 s; };
    U ua, ub; ua.h = a; ub.h = b;
    return __builtin_amdgcn_mfma_f32_16x16x16bf16_1k(ua.s, ub.s, c, 0, 0, 0);
#endif
}

// ---------------------------------------------------------------------------
// Fused prep: one launch does
//   blocks [0,1728)    : W_attn [768][2304] -> WaT [2304][768] bf16 (32x32 tiles)
//   blocks [1728,2304) : W_proj [768][768]  -> WpT [768][768]  bf16
//   blocks [2304,3840) : x fp32 -> bf16 streaming convert
// ---------------------------------------------------------------------------
__global__ __launch_bounds__(256) void prep_kernel(
    const float* __restrict__ Wa, bf16_t* __restrict__ WaT,
    const float* __restrict__ Wp, bf16_t* __restrict__ WpT,
    const float* __restrict__ x,  bf16_t* __restrict__ xb)
{
    __shared__ float tile[32][33];
    const int bid = blockIdx.x;
    if (bid < 2304) {
        // transpose+convert job
        const float* W; bf16_t* WT; int K, N, b;
        if (bid < 1728) { W = Wa; WT = WaT; K = 768; N = 2304; b = bid; }
        else            { W = Wp; WT = WpT; K = 768; N = 768;  b = bid - 1728; }
        const int nb = N / 32;
        const int n0 = (b % nb) * 32, k0 = (b / nb) * 32;
        const int tx = threadIdx.x & 31, ty = threadIdx.x >> 5;   // ty 0..7
#pragma unroll
        for (int i = 0; i < 32; i += 8)
            tile[ty + i][tx] = W[(size_t)(k0 + ty + i) * N + (n0 + tx)];
        __syncthreads();
#pragma unroll
        for (int i = 0; i < 32; i += 8)
            WT[(size_t)(n0 + ty + i) * K + (k0 + tx)] = (bf16_t)tile[tx][ty + i];
    } else {
        // x convert job: 1536 blocks, grid-stride over n8 = MROWS*EMB/8
        const int n8 = MROWS * EMB / 8;
        int idx    = (bid - 2304) * 256 + threadIdx.x;
        const int stride = 1536 * 256;
        for (int i = idx; i < n8; i += stride) {
            float4 a = ((const float4*)x)[i * 2];
            float4 b = ((const float4*)x)[i * 2 + 1];
            bf16x8 v;
            v[0] = (bf16_t)a.x; v[1] = (bf16_t)a.y; v[2] = (bf16_t)a.z; v[3] = (bf16_t)a.w;
            v[4] = (bf16_t)b.x; v[5] = (bf16_t)b.y; v[6] = (bf16_t)b.z; v[7] = (bf16_t)b.w;
            ((bf16x8*)xb)[i] = v;
        }
    }
}

// ---------------------------------------------------------------------------
// QKV GEMM (proven structure, 128x128 tile, BK=32, m97-style dbuf, XCD
// swizzle): C[M][N3] = A[M][768] * BT^T + bias. bf16 out; Q pre-scaled;
// V written transposed [bh][d][s].
// Round 10: epilogue strength reduction — one base address per (i,j) cell,
// r-stores at compile-time offset r*HDIM (the 4 r values are 4 consecutive s
// in the same batch: s0 = gm0&2047 <= 2044). Cuts ~500 epilogue VALU/thread.
// ---------------------------------------------------------------------------
template<int MODE>
__global__ __launch_bounds__(256) void gemm_kernel(
    const bf16_t* __restrict__ Av,
    const bf16_t* __restrict__ BT,
    const float* __restrict__ bias,
    float* __restrict__ out,
    bf16_t* __restrict__ qbuf,
    bf16_t* __restrict__ kbuf,
    bf16_t* __restrict__ vbuf,
    int Ncols)
{
    const int K = 768;
    __shared__ alignas(16) bf16_t As[2][128 * 32];
    __shared__ alignas(16) bf16_t Bs[2][128 * 32];

    const int tid    = threadIdx.x;
    const int wave   = tid >> 6;
    const int lane   = tid & 63;
    const int lane15 = lane & 15;
    const int quad   = lane >> 4;

    // bijective XCD swizzle: swz = (bid%8)*chunk + bid/8; chunk = grid/8.
    const int bid   = blockIdx.x;
    const int chunk = (int)(gridDim.x >> 3);
    const int swz   = (bid & 7) * chunk + (bid >> 3);
    const int NB    = Ncols >> 7;            // N-blocks (18)
    const int mBase = (swz / NB) * 128;
    const int nBase = (swz % NB) * 128;

    const int wm = (wave >> 1) * 64;
    const int wn = (wave & 1) * 64;

    f32x4 acc[4][4];
#pragma unroll
    for (int i = 0; i < 4; i++)
#pragma unroll
        for (int j = 0; j < 4; j++) acc[i][j] = (f32x4){0.f, 0.f, 0.f, 0.f};

    const bf16_t* aSrc = Av + (size_t)mBase * K;
    const bf16_t* bSrc = BT + (size_t)nBase * K;

    const int srow = lane >> 2;      // 0..15 within 16-row group
    const int sch  = lane & 3;       // physical chunk this lane fills

    auto issueA = [&](int k0, int buf) {
#pragma unroll
        for (int p = 0; p < 2; p++) {
            int r0  = p * 64 + wave * 16;
            int row = r0 + srow;
            int lch = sch ^ (row & 3);
            gld_lds16(&As[buf][r0 * 32], aSrc + (size_t)row * K + k0 + lch * 8);
        }
    };
    auto issueB = [&](int k0, int buf) {
#pragma unroll
        for (int p = 0; p < 2; p++) {
            int r0  = p * 64 + wave * 16;
            int row = r0 + srow;
            int lch = sch ^ (row & 3);
            gld_lds16(&Bs[buf][r0 * 32], bSrc + (size_t)row * K + k0 + lch * 8);
        }
    };

    issueA(0, 0);
    issueB(0, 0);

    for (int k0 = 0, it = 0; k0 < K; k0 += 32, it++) {
        const int buf = it & 1;
        __syncthreads();
        if (k0 + 32 < K) {
            issueB(k0 + 32, buf ^ 1);
            issueA(k0 + 32, buf ^ 1);
        }

        bf16x8 aF[4], bF[4];
#pragma unroll
        for (int t = 0; t < 4; t++) {
            int ra = wm + t * 16 + lane15;
            int rb = wn + t * 16 + lane15;
            aF[t] = *(const bf16x8*)&As[buf][ra * 32 + (quad ^ (ra & 3)) * 8];
            bF[t] = *(const bf16x8*)&Bs[buf][rb * 32 + (quad ^ (rb & 3)) * 8];
        }
#pragma unroll
        for (int i = 0; i < 4; i++)
#pragma unroll
            for (int j = 0; j < 4; j++)
                acc[i][j] = __builtin_amdgcn_mfma_f32_16x16x32_bf16(aF[i], bF[j], acc[i][j], 0, 0, 0);
    }

    const int region = nBase / EMB;          // wave-uniform (768%128==0)
#pragma unroll
    for (int i = 0; i < 4; i++) {
#pragma unroll
        for (int j = 0; j < 4; j++) {
            int gn = nBase + wn + j * 16 + lane15;
            float bv = bias[gn];
            int gm0 = mBase + wm + i * 16 + quad * 4;      // r=0 row; all 4 r same batch
            int b = gm0 >> 11, s0 = gm0 & 2047;
            if (region == 2) {
                // V: direct transposed write [bh][d][s]; 4 consecutive s -> 8 B store
                int within = gn - 2 * EMB;
                int h = within >> 6, d = within & 63;
                int bh = b * NHEAD + h;
                bf16x4 v4;
#pragma unroll
                for (int r = 0; r < 4; r++) v4[r] = (bf16_t)(acc[i][j][r] + bv);
                *(bf16x4*)&vbuf[((size_t)bh * HDIM + d) * SEQ + s0] = v4;
            } else {
                bf16_t* dst = (region == 0) ? qbuf : kbuf;
                const float scale = (region == 0) ? QSCALE : 1.0f;
                int within = gn - region * EMB;
                int h = within >> 6, d = within & 63;
                // one base address; r-stores at constant offset r*HDIM (s0+r)
                bf16_t* p = dst + ((size_t)(b * NHEAD + h) * SEQ + s0) * HDIM + d;
#pragma unroll
                for (int r = 0; r < 4; r++)
                    p[r * HDIM] = (bf16_t)((acc[i][j][r] + bv) * scale);
            }
        }
    }
}

// ---------------------------------------------------------------------------
// Proj GEMM — TM=64 x TN=128, BK=64, LDS 48 KB, 3 blocks/CU, XCD swizzle.
// ---------------------------------------------------------------------------
__global__ __launch_bounds__(256) void proj_kernel(
    const bf16_t* __restrict__ Av,    // [8192][768] bf16 (attn output)
    const bf16_t* __restrict__ BT,    // [768][768] bf16
    const float*  __restrict__ bias,
    float* __restrict__ out)          // [8192][768] fp32
{
    const int K = 768;
    __shared__ alignas(16) bf16_t As[2][64 * 64];     // 8 KB/buf
    __shared__ alignas(16) bf16_t Bs[2][128 * 64];    // 16 KB/buf

    const int tid    = threadIdx.x;
    const int wave   = tid >> 6;
    const int lane   = tid & 63;
    const int lane15 = lane & 15;
    const int quad   = lane >> 4;

    // bijective XCD swizzle: 768 blocks = 8 * 96.
    const int bid   = blockIdx.x;
    const int swz   = (bid & 7) * 96 + (bid >> 3);
    const int mBase = (swz / 6) * 64;
    const int nBase = (swz % 6) * 128;

    f32x4 acc[4][2];
#pragma unroll
    for (int t = 0; t < 4; t++)
#pragma unroll
        for (int u = 0; u < 2; u++) acc[t][u] = (f32x4){0.f, 0.f, 0.f, 0.f};

    const bf16_t* aSrc = Av + (size_t)mBase * K;
    const bf16_t* bSrc = BT + (size_t)nBase * K;

    const int srow8 = lane >> 3;   // row within 8-row issue
    const int sch8  = lane & 7;    // physical chunk this lane fills

    auto issueA = [&](int k0, int buf) {
#pragma unroll
        for (int p = 0; p < 2; p++) {
            int r0  = wave * 8 + p * 32;             // 4 waves x 2 = 64 rows
            int row = r0 + srow8;
            int lch = sch8 ^ (row & 7);
            gld_lds16(&As[buf][r0 * 64], aSrc + (size_t)row * K + k0 + lch * 8);
        }
    };
    auto issueB = [&](int k0, int buf) {
#pragma unroll
        for (int p = 0; p < 4; p++) {
            int r0  = wave * 8 + p * 32;             // 4 waves x 4 = 128 rows
            int row = r0 + srow8;
            int lch = sch8 ^ (row & 7);
            gld_lds16(&Bs[buf][r0 * 64], bSrc + (size_t)row * K + k0 + lch * 8);
        }
    };

    issueA(0, 0);
    issueB(0, 0);

    for (int k0 = 0, it = 0; k0 < K; k0 += 64, it++) {
        const int buf = it & 1;
        __syncthreads();
        if (k0 + 64 < K) {
            issueB(k0 + 64, buf ^ 1);
            issueA(k0 + 64, buf ^ 1);
        }

        bf16x8 aF[2][4], bF[2][2];
#pragma unroll
        for (int kk = 0; kk < 2; kk++) {
#pragma unroll
            for (int t = 0; t < 4; t++) {
                int ra = t * 16 + lane15;
                aF[kk][t] = *(const bf16x8*)&As[buf][ra * 64 + (((quad + kk * 4) ^ (ra & 7)) * 8)];
            }
#pragma unroll
            for (int u = 0; u < 2; u++) {
                int rb = wave * 32 + u * 16 + lane15;
                bF[kk][u] = *(const bf16x8*)&Bs[buf][rb * 64 + (((quad + kk * 4) ^ (rb & 7)) * 8)];
            }
        }
#pragma unroll
        for (int kk = 0; kk < 2; kk++)
#pragma unroll
            for (int t = 0; t < 4; t++)
#pragma unroll
                for (int u = 0; u < 2; u++)
                    acc[t][u] = __builtin_amdgcn_mfma_f32_16x16x32_bf16(aF[kk][t], bF[kk][u], acc[t][u], 0, 0, 0);
    }

#pragma unroll
    for (int t = 0; t < 4; t++) {
#pragma unroll
        for (int u = 0; u < 2; u++) {
            int gn = nBase + wave * 32 + u * 16 + lane15;
            float bv = bias[gn];
#pragma unroll
            for (int r = 0; r < 4; r++) {
                int gm = mBase + t * 16 + quad * 4 + r;
                out[(size_t)gm * EMB + gn] = acc[t][u][r] + bv;
            }
        }
    }
}

// ---------------------------------------------------------------------------
// Flash attention, causal — unchanged from round 9: merged-pair {j,31-j} key
// loop (uniform 33 quanta/block, stagings 32-j), KVBLK=64 / LDS 41 KB /
// 3 blocks/CU, K-fragment hoist shared by both q-sub-tiles, transposed
// scores, exp2 softmax, setprio, XCD swizzle.
// ---------------------------------------------------------------------------
__global__ __launch_bounds__(256) void attn_kernel(
    const bf16_t* __restrict__ qbuf,
    const bf16_t* __restrict__ kbuf,
    const bf16_t* __restrict__ vtbuf,
    bf16_t* __restrict__ obuf)
{
    __shared__ alignas(16) bf16_t Ks[2][64 * 64];     // [key][dim], dbuf 16 KB
    __shared__ alignas(16) bf16_t Vs[2][64 * 64];     // [dim][key], dbuf 16 KB
    __shared__ alignas(16) bf16_t Plds[4][16 * 72];   // per-wave O-transpose scratch

    const int tid    = threadIdx.x;
    const int wave   = tid >> 6;
    const int lane   = tid & 63;
    const int lane15 = lane & 15;
    const int quad   = lane >> 4;

    // bijective XCD swizzle: 768 blocks = 8 * 96.
    const int bid = blockIdx.x;
    const int swz = (bid & 7) * 96 + (bid >> 3);
    const int bh = swz >> 4;
    const int j  = swz & 15;

    const bf16_t* Qp = qbuf  + (size_t)bh * SEQ * HDIM;
    const bf16_t* Kp = kbuf  + (size_t)bh * SEQ * HDIM;
    const bf16_t* Vp = vtbuf + (size_t)bh * HDIM * SEQ;
    bf16_t* pl = &Plds[wave][0];
    const int b = bh / NHEAD, h = bh % NHEAD;

    const int srow8 = lane >> 3;   // 0..7 within 8-row group
    const int sch8  = lane & 7;    // physical chunk this lane fills

    auto issueKV = [&](int kb, int buf) {
#pragma unroll
        for (int p = 0; p < 2; p++) {
            int r0  = p * 32 + wave * 8;             // wave-uniform
            int row = r0 + srow8;
            int lch = sch8 ^ (row & 7);              // logical chunk to fetch
            gld_lds16(&Ks[buf][r0 * 64], Kp + (size_t)(kb + row) * HDIM + lch * 8);
            gld_lds16(&Vs[buf][r0 * 64], Vp + (size_t)row * SEQ + kb + lch * 8);
        }
    };

    // sub-tile 0: q-tile j (keys kt<=j); sub-tile 1: q-tile 31-j (all kt)
    const int q0s[2] = { j * 64 + wave * 16, (31 - j) * 64 + wave * 16 };

    bf16x8 qf[2][2];
#pragma unroll
    for (int qq = 0; qq < 2; qq++) {
        qf[qq][0] = *(const bf16x8*)&Qp[(size_t)(q0s[qq] + lane15) * HDIM + quad * 8];
        qf[qq][1] = *(const bf16x8*)&Qp[(size_t)(q0s[qq] + lane15) * HDIM + 32 + quad * 8];
    }

    float lrow[2] = {0.f, 0.f};
    f32x4 oT[2][4];
#pragma unroll
    for (int qq = 0; qq < 2; qq++)
#pragma unroll
        for (int t = 0; t < 4; t++) oT[qq][t] = (f32x4){0.f, 0.f, 0.f, 0.f};

    const int nT = 32 - j;                   // stagings: B's full key range
    issueKV(0, 0);

    for (int kt = 0; kt < nT; kt++) {
        const int buf = kt & 1;
        __syncthreads();                                   // tile kt ready
        if (kt + 1 < nT) issueKV((kt + 1) * 64, buf ^ 1);  // prefetch

        const int kb = kt * 64;

        // hoist K fragments once per tile; shared by both q-sub-tiles
        bf16x8 kf[4][2];
#pragma unroll
        for (int kg = 0; kg < 4; kg++) {
            int row = kg * 16 + lane15;
            kf[kg][0] = *(const bf16x8*)&Ks[buf][row * 64 + ((quad    ) ^ (row & 7)) * 8];
            kf[kg][1] = *(const bf16x8*)&Ks[buf][row * 64 + ((quad + 4) ^ (row & 7)) * 8];
        }

#pragma unroll
        for (int qq = 0; qq < 2; qq++) {
            const int q0q = q0s[qq];
            if (qq == 0 && kt > j) continue;   // A done (wave-uniform branch)

            // QK^T -> S^T[key][query]: A = K fragment, B = Q fragment
            f32x4 sT[4];
            __builtin_amdgcn_s_setprio(1);
#pragma unroll
            for (int kg = 0; kg < 4; kg++) {
                sT[kg] = (f32x4){0.f, 0.f, 0.f, 0.f};
                sT[kg] = __builtin_amdgcn_mfma_f32_16x16x32_bf16(kf[kg][0], qf[qq][0], sT[kg], 0, 0, 0);
                sT[kg] = __builtin_amdgcn_mfma_f32_16x16x32_bf16(kf[kg][1], qf[qq][1], sT[kg], 0, 0, 0);
            }
            __builtin_amdgcn_s_setprio(0);

            // causal mask: only the diagonal tile (wave-uniform test)
            if (kb + 64 > q0q) {
                const int query = q0q + lane15;
#pragma unroll
                for (int kg = 0; kg < 4; kg++) {
                    int key0 = kb + kg * 16 + quad * 4;
#pragma unroll
                    for (int r = 0; r < 4; r++)
                        sT[kg][r] = (key0 + r <= query) ? sT[kg][r] : -1e30f;
                }
            }

            // unnormalized softmax: P^T = exp2(S^T); l += sum; pack to bf16
            bf16x4 pf[4];
#pragma unroll
            for (int kg = 0; kg < 4; kg++) {
#pragma unroll
                for (int r = 0; r < 4; r++) sT[kg][r] = fast_exp2(sT[kg][r]);
                lrow[qq] += (sT[kg][0] + sT[kg][1]) + (sT[kg][2] + sT[kg][3]);
                bf16x4 v;
#pragma unroll
                for (int r = 0; r < 4; r++) v[r] = (bf16_t)sT[kg][r];
                pf[kg] = v;
            }

            // PV: O^T[d][q] += V^T[d][k] * P^T[k][q], 16x16x16 MFMAs.
            __builtin_amdgcn_s_setprio(1);
#pragma unroll
            for (int t = 0; t < 4; t++) {
                int vrow = t * 16 + lane15;
#pragma unroll
                for (int kg = 0; kg < 4; kg++) {
                    int c    = kg * 2 + (quad >> 1);           // logical 8-elem chunk
                    int phys = c ^ (vrow & 7);
                    bf16x4 vf = *(const bf16x4*)&Vs[buf][vrow * 64 + phys * 8 + (quad & 1) * 4];
                    oT[qq][t] = mfma16_bf16(vf, pf[kg], oT[qq][t]);
                }
            }
            __builtin_amdgcn_s_setprio(0);
        }
    }

    // epilogue per sub-tile: l-reduce, O^T -> LDS -> coalesced global write
#pragma unroll
    for (int qq = 0; qq < 2; qq++) {
        const int q0q = q0s[qq];
        float l = lrow[qq];
        l += __shfl_xor(l, 16, 64);
        l += __shfl_xor(l, 32, 64);
        const float inv = 1.0f / l;

#pragma unroll
        for (int t = 0; t < 4; t++)
#pragma unroll
            for (int r = 0; r < 4; r++)
                pl[lane15 * 72 + t * 16 + quad * 4 + r] = (bf16_t)(oT[qq][t][r] * inv);

        const int qrow = lane >> 2;      // 0..15 query within sub-tile
        const int ch   = lane & 3;       // 8-elem d-chunk
        bf16_t* orow = &obuf[((size_t)(b * SEQ + q0q + qrow)) * EMB + h * HDIM];
#pragma unroll
        for (int p = 0; p < 2; p++) {
            bf16x8 v = *(const bf16x8*)&pl[qrow * 72 + (ch + p * 4) * 8];
            *(bf16x8*)&orow[(ch + p * 4) * 8] = v;
        }
    }
}

// ---------------------------------------------------------------------------
extern "C" void kernel_launch(void* const* d_in, const int* in_sizes, int n_in,
                              void* d_out, int out_size, void* d_ws, size_t ws_size,
                              hipStream_t stream) {
    const float* x      = (const float*)d_in[0];
    // d_in[1] = mask: causal by construction, implemented analytically
    const float* W_attn = (const float*)d_in[2];
    const float* b_attn = (const float*)d_in[3];
    const float* W_proj = (const float*)d_in[4];
    const float* b_proj = (const float*)d_in[5];
    float* out = (float*)d_out;   // fp32 output

    bf16_t* ws  = (bf16_t*)d_ws;
    bf16_t* WaT = ws;                                         // [2304][768]
    bf16_t* WpT = WaT + (size_t)N3 * EMB;                     // [768][768]
    bf16_t* Qb  = WpT + (size_t)EMB * EMB;                    // [B*H][S][D]
    bf16_t* Kb  = Qb + (size_t)BATCH * NHEAD * SEQ * HDIM;
    bf16_t* Vt  = Kb + (size_t)BATCH * NHEAD * SEQ * HDIM;    // [B*H][D][S]
    bf16_t* Ob  = Vt + (size_t)BATCH * NHEAD * SEQ * HDIM;    // [8192][768]
    bf16_t* xb  = Ob;   // alias: bf16 x is dead before attn writes Ob

    // one prep launch: both W transposes + x convert
    prep_kernel<<<3840, 256, 0, stream>>>(W_attn, WaT, W_proj, WpT, x, xb);

    // QKV: 1152 blocks (64 M x 18 N), XCD-swizzled inside the kernel.
    gemm_kernel<1><<<1152, 256, 0, stream>>>(
        xb, WaT, b_attn, nullptr, Qb, Kb, Vt, N3);

    // attn: 768 blocks = (bh, pair {j,31-j}), merged key loop, uniform work.
    attn_kernel<<<768, 256, 0, stream>>>(Qb, Kb, Vt, Ob);

    // proj: 768 blocks (128 M x 6 N), TM=64 x TN=128, BK=64, XCD-swizzled.
    proj_kernel<<<768, 256, 0, stream>>>(Ob, WpT, b_proj, out);
}

// Round 11
// 202.648 us; speedup vs baseline: 1.1329x; 1.0711x over previous
//
#include <hip/hip_runtime.h>
#include <stdint.h>

// Problem constants
#define NHEAD 12
#define HDIM  64
#define EMB   768
#define N3    2304      // 3*EMB
#define SEQ   2048
#define BATCH 4
#define MROWS 8192      // BATCH*SEQ

// 0.125 * log2(e): folds the 1/sqrt(64) scale AND the e->2 base change into Q.
#define QSCALE 0.18033688011112042f

typedef __bf16 bf16_t;
typedef __bf16 bf16x8 __attribute__((ext_vector_type(8)));
typedef __bf16 bf16x4 __attribute__((ext_vector_type(4)));
typedef short  s16x4  __attribute__((ext_vector_type(4)));
typedef float  f32x4  __attribute__((ext_vector_type(4)));

// async global->LDS, 16 B/lane. HW scatters lane i to (readfirstlane(lds)) + i*16.
__device__ __forceinline__ void gld_lds16(void* lds, const void* g) {
    __builtin_amdgcn_global_load_lds((const __attribute__((address_space(1))) void*)g,
                                     (__attribute__((address_space(3))) void*)lds,
                                     16, 0, 0);
}

// raw v_exp_f32 (2^x): args are provably in-range; skips libm denormal fixup.
__device__ __forceinline__ float fast_exp2(float x) {
    return __builtin_amdgcn_exp2f(x);
}

// 16x16x16 bf16 MFMA (K=16): A 2 VGPR / B 2 VGPR / C-D 4 (cdna4_isa §10).
__device__ __forceinline__ f32x4 mfma16_bf16(bf16x4 a, bf16x4 b, f32x4 c) {
#if __has_builtin(__builtin_amdgcn_mfma_f32_16x16x16_bf16)
    return __builtin_amdgcn_mfma_f32_16x16x16_bf16(a, b, c, 0, 0, 0);
#else
    union U { bf16x4 h; s16x4 s; };
    U ua, ub; ua.h = a; ub.h = b;
    return __builtin_amdgcn_mfma_f32_16x16x16bf16_1k(ua.s, ub.s, c, 0, 0, 0);
#endif
}

// ---------------------------------------------------------------------------
// Fused prep: one launch does
//   blocks [0,1728)    : W_attn [768][2304] -> WaT [2304][768] bf16 (32x32 tiles)
//   blocks [1728,2304) : W_proj [768][768]  -> WpT [768][768]  bf16
//   blocks [2304,3840) : x fp32 -> bf16 streaming convert
// ---------------------------------------------------------------------------
__global__ __launch_bounds__(256) void prep_kernel(
    const float* __restrict__ Wa, bf16_t* __restrict__ WaT,
    const float* __restrict__ Wp, bf16_t* __restrict__ WpT,
    const float* __restrict__ x,  bf16_t* __restrict__ xb)
{
    __shared__ float tile[32][33];
    const int bid = blockIdx.x;
    if (bid < 2304) {
        // transpose+convert job
        const float* W; bf16_t* WT; int K, N, b;
        if (bid < 1728) { W = Wa; WT = WaT; K = 768; N = 2304; b = bid; }
        else            { W = Wp; WT = WpT; K = 768; N = 768;  b = bid - 1728; }
        const int nb = N / 32;
        const int n0 = (b % nb) * 32, k0 = (b / nb) * 32;
        const int tx = threadIdx.x & 31, ty = threadIdx.x >> 5;   // ty 0..7
#pragma unroll
        for (int i = 0; i < 32; i += 8)
            tile[ty + i][tx] = W[(size_t)(k0 + ty + i) * N + (n0 + tx)];
        __syncthreads();
#pragma unroll
        for (int i = 0; i < 32; i += 8)
            WT[(size_t)(n0 + ty + i) * K + (k0 + tx)] = (bf16_t)tile[tx][ty + i];
    } else {
        // x convert job: 1536 blocks, grid-stride over n8 = MROWS*EMB/8
        const int n8 = MROWS * EMB / 8;
        int idx    = (bid - 2304) * 256 + threadIdx.x;
        const int stride = 1536 * 256;
        for (int i = idx; i < n8; i += stride) {
            float4 a = ((const float4*)x)[i * 2];
            float4 b = ((const float4*)x)[i * 2 + 1];
            bf16x8 v;
            v[0] = (bf16_t)a.x; v[1] = (bf16_t)a.y; v[2] = (bf16_t)a.z; v[3] = (bf16_t)a.w;
            v[4] = (bf16_t)b.x; v[5] = (bf16_t)b.y; v[6] = (bf16_t)b.z; v[7] = (bf16_t)b.w;
            ((bf16x8*)xb)[i] = v;
        }
    }
}

// ---------------------------------------------------------------------------
// QKV GEMM — round 11: 128x192 tile (BK=32, m97-style dbuf, XCD swizzle).
// Grid 768 = 64 M x 12 N = EXACTLY 3 resident blocks/CU (LDS 40 KB, VGPR
// capped via launch_bounds(256,3)): kills the 1152-block 2.25-round tail.
// Per wave: 64x96 output = 4x6 frags -> 24 MFMA : 10 ds_read_b128 per
// barrier-pair (was 16:8); total barrier-drain events -33%.
// bf16 out; Q pre-scaled; V written transposed [bh][d][s].
// ---------------------------------------------------------------------------
__global__ __launch_bounds__(256, 3) void gemm_kernel(
    const bf16_t* __restrict__ Av,
    const bf16_t* __restrict__ BT,
    const float* __restrict__ bias,
    bf16_t* __restrict__ qbuf,
    bf16_t* __restrict__ kbuf,
    bf16_t* __restrict__ vbuf)
{
    const int K = 768;
    __shared__ alignas(16) bf16_t As[2][128 * 32];    // 8 KB/buf
    __shared__ alignas(16) bf16_t Bs[2][192 * 32];    // 12 KB/buf

    const int tid    = threadIdx.x;
    const int wave   = tid >> 6;
    const int lane   = tid & 63;
    const int lane15 = lane & 15;
    const int quad   = lane >> 4;

    // bijective XCD swizzle: 768 blocks = 8 * 96.
    const int bid   = blockIdx.x;
    const int swz   = (bid & 7) * 96 + (bid >> 3);
    const int mBase = (swz / 12) * 128;
    const int nBase = (swz % 12) * 192;

    const int wm = (wave >> 1) * 64;     // 2 wave-rows x 64
    const int wn = (wave & 1) * 96;      // 2 wave-cols x 96

    f32x4 acc[4][6];
#pragma unroll
    for (int i = 0; i < 4; i++)
#pragma unroll
        for (int j = 0; j < 6; j++) acc[i][j] = (f32x4){0.f, 0.f, 0.f, 0.f};

    const bf16_t* aSrc = Av + (size_t)mBase * K;
    const bf16_t* bSrc = BT + (size_t)nBase * K;

    const int srow = lane >> 2;      // 0..15 within 16-row group
    const int sch  = lane & 3;       // physical chunk this lane fills

    auto issueA = [&](int k0, int buf) {
#pragma unroll
        for (int p = 0; p < 2; p++) {
            int r0  = p * 64 + wave * 16;
            int row = r0 + srow;
            int lch = sch ^ (row & 3);
            gld_lds16(&As[buf][r0 * 32], aSrc + (size_t)row * K + k0 + lch * 8);
        }
    };
    auto issueB = [&](int k0, int buf) {
#pragma unroll
        for (int p = 0; p < 3; p++) {
            int r0  = p * 64 + wave * 16;           // covers 192 rows
            int row = r0 + srow;
            int lch = sch ^ (row & 3);
            gld_lds16(&Bs[buf][r0 * 32], bSrc + (size_t)row * K + k0 + lch * 8);
        }
    };

    issueA(0, 0);
    issueB(0, 0);

    for (int k0 = 0, it = 0; k0 < K; k0 += 32, it++) {
        const int buf = it & 1;
        __syncthreads();
        if (k0 + 32 < K) {
            issueB(k0 + 32, buf ^ 1);
            issueA(k0 + 32, buf ^ 1);
        }

        bf16x8 aF[4], bF[6];
#pragma unroll
        for (int t = 0; t < 4; t++) {
            int ra = wm + t * 16 + lane15;
            aF[t] = *(const bf16x8*)&As[buf][ra * 32 + (quad ^ (ra & 3)) * 8];
        }
#pragma unroll
        for (int u = 0; u < 6; u++) {
            int rb = wn + u * 16 + lane15;
            bF[u] = *(const bf16x8*)&Bs[buf][rb * 32 + (quad ^ (rb & 3)) * 8];
        }
#pragma unroll
        for (int i = 0; i < 4; i++)
#pragma unroll
            for (int j = 0; j < 6; j++)
                acc[i][j] = __builtin_amdgcn_mfma_f32_16x16x32_bf16(aF[i], bF[j], acc[i][j], 0, 0, 0);
    }

    const int region = nBase / EMB;          // uniform per block (768%192==0 within region)
#pragma unroll
    for (int i = 0; i < 4; i++) {
#pragma unroll
        for (int j = 0; j < 6; j++) {
            int gn = nBase + wn + j * 16 + lane15;
            float bv = bias[gn];
            int gm0 = mBase + wm + i * 16 + quad * 4;      // 4 r values same batch
            int b = gm0 >> 11, s0 = gm0 & 2047;
            int within = gn - region * EMB;
            int h = within >> 6, d = within & 63;
            if (region == 2) {
                // V: direct transposed write [bh][d][s]; 4 consecutive s -> 8 B store
                int bh = b * NHEAD + h;
                bf16x4 v4;
#pragma unroll
                for (int r = 0; r < 4; r++) v4[r] = (bf16_t)(acc[i][j][r] + bv);
                *(bf16x4*)&vbuf[((size_t)bh * HDIM + d) * SEQ + s0] = v4;
            } else {
                bf16_t* dst = (region == 0) ? qbuf : kbuf;
                const float scale = (region == 0) ? QSCALE : 1.0f;
                bf16_t* p = dst + ((size_t)(b * NHEAD + h) * SEQ + s0) * HDIM + d;
#pragma unroll
                for (int r = 0; r < 4; r++)
                    p[r * HDIM] = (bf16_t)((acc[i][j][r] + bv) * scale);
            }
        }
    }
}

// ---------------------------------------------------------------------------
// Proj GEMM — TM=64 x TN=128, BK=64, LDS 48 KB, 3 blocks/CU, XCD swizzle.
// ---------------------------------------------------------------------------
__global__ __launch_bounds__(256) void proj_kernel(
    const bf16_t* __restrict__ Av,    // [8192][768] bf16 (attn output)
    const bf16_t* __restrict__ BT,    // [768][768] bf16
    const float*  __restrict__ bias,
    float* __restrict__ out)          // [8192][768] fp32
{
    const int K = 768;
    __shared__ alignas(16) bf16_t As[2][64 * 64];     // 8 KB/buf
    __shared__ alignas(16) bf16_t Bs[2][128 * 64];    // 16 KB/buf

    const int tid    = threadIdx.x;
    const int wave   = tid >> 6;
    const int lane   = tid & 63;
    const int lane15 = lane & 15;
    const int quad   = lane >> 4;

    // bijective XCD swizzle: 768 blocks = 8 * 96.
    const int bid   = blockIdx.x;
    const int swz   = (bid & 7) * 96 + (bid >> 3);
    const int mBase = (swz / 6) * 64;
    const int nBase = (swz % 6) * 128;

    f32x4 acc[4][2];
#pragma unroll
    for (int t = 0; t < 4; t++)
#pragma unroll
        for (int u = 0; u < 2; u++) acc[t][u] = (f32x4){0.f, 0.f, 0.f, 0.f};

    const bf16_t* aSrc = Av + (size_t)mBase * K;
    const bf16_t* bSrc = BT + (size_t)nBase * K;

    const int srow8 = lane >> 3;   // row within 8-row issue
    const int sch8  = lane & 7;    // physical chunk this lane fills

    auto issueA = [&](int k0, int buf) {
#pragma unroll
        for (int p = 0; p < 2; p++) {
            int r0  = wave * 8 + p * 32;             // 4 waves x 2 = 64 rows
            int row = r0 + srow8;
            int lch = sch8 ^ (row & 7);
            gld_lds16(&As[buf][r0 * 64], aSrc + (size_t)row * K + k0 + lch * 8);
        }
    };
    auto issueB = [&](int k0, int buf) {
#pragma unroll
        for (int p = 0; p < 4; p++) {
            int r0  = wave * 8 + p * 32;             // 4 waves x 4 = 128 rows
            int row = r0 + srow8;
            int lch = sch8 ^ (row & 7);
            gld_lds16(&Bs[buf][r0 * 64], bSrc + (size_t)row * K + k0 + lch * 8);
        }
    };

    issueA(0, 0);
    issueB(0, 0);

    for (int k0 = 0, it = 0; k0 < K; k0 += 64, it++) {
        const int buf = it & 1;
        __syncthreads();
        if (k0 + 64 < K) {
            issueB(k0 + 64, buf ^ 1);
            issueA(k0 + 64, buf ^ 1);
        }

        bf16x8 aF[2][4], bF[2][2];
#pragma unroll
        for (int kk = 0; kk < 2; kk++) {
#pragma unroll
            for (int t = 0; t < 4; t++) {
                int ra = t * 16 + lane15;
                aF[kk][t] = *(const bf16x8*)&As[buf][ra * 64 + (((quad + kk * 4) ^ (ra & 7)) * 8)];
            }
#pragma unroll
            for (int u = 0; u < 2; u++) {
                int rb = wave * 32 + u * 16 + lane15;
                bF[kk][u] = *(const bf16x8*)&Bs[buf][rb * 64 + (((quad + kk * 4) ^ (rb & 7)) * 8)];
            }
        }
#pragma unroll
        for (int kk = 0; kk < 2; kk++)
#pragma unroll
            for (int t = 0; t < 4; t++)
#pragma unroll
                for (int u = 0; u < 2; u++)
                    acc[t][u] = __builtin_amdgcn_mfma_f32_16x16x32_bf16(aF[kk][t], bF[kk][u], acc[t][u], 0, 0, 0);
    }

#pragma unroll
    for (int t = 0; t < 4; t++) {
#pragma unroll
        for (int u = 0; u < 2; u++) {
            int gn = nBase + wave * 32 + u * 16 + lane15;
            float bv = bias[gn];
#pragma unroll
            for (int r = 0; r < 4; r++) {
                int gm = mBase + t * 16 + quad * 4 + r;
                out[(size_t)gm * EMB + gn] = acc[t][u][r] + bv;
            }
        }
    }
}

// ---------------------------------------------------------------------------
// Flash attention, causal — unchanged: merged-pair {j,31-j} key loop (uniform
// 33 quanta/block, stagings 32-j), KVBLK=64 / LDS 41 KB / 3 blocks/CU,
// K-fragment hoist shared by both q-sub-tiles, transposed scores, exp2
// softmax, setprio, XCD swizzle.
// ---------------------------------------------------------------------------
__global__ __launch_bounds__(256) void attn_kernel(
    const bf16_t* __restrict__ qbuf,
    const bf16_t* __restrict__ kbuf,
    const bf16_t* __restrict__ vtbuf,
    bf16_t* __restrict__ obuf)
{
    __shared__ alignas(16) bf16_t Ks[2][64 * 64];     // [key][dim], dbuf 16 KB
    __shared__ alignas(16) bf16_t Vs[2][64 * 64];     // [dim][key], dbuf 16 KB
    __shared__ alignas(16) bf16_t Plds[4][16 * 72];   // per-wave O-transpose scratch

    const int tid    = threadIdx.x;
    const int wave   = tid >> 6;
    const int lane   = tid & 63;
    const int lane15 = lane & 15;
    const int quad   = lane >> 4;

    // bijective XCD swizzle: 768 blocks = 8 * 96.
    const int bid = blockIdx.x;
    const int swz = (bid & 7) * 96 + (bid >> 3);
    const int bh = swz >> 4;
    const int j  = swz & 15;

    const bf16_t* Qp = qbuf  + (size_t)bh * SEQ * HDIM;
    const bf16_t* Kp = kbuf  + (size_t)bh * SEQ * HDIM;
    const bf16_t* Vp = vtbuf + (size_t)bh * HDIM * SEQ;
    bf16_t* pl = &Plds[wave][0];
    const int b = bh / NHEAD, h = bh % NHEAD;

    const int srow8 = lane >> 3;   // 0..7 within 8-row group
    const int sch8  = lane & 7;    // physical chunk this lane fills

    auto issueKV = [&](int kb, int buf) {
#pragma unroll
        for (int p = 0; p < 2; p++) {
            int r0  = p * 32 + wave * 8;             // wave-uniform
            int row = r0 + srow8;
            int lch = sch8 ^ (row & 7);              // logical chunk to fetch
            gld_lds16(&Ks[buf][r0 * 64], Kp + (size_t)(kb + row) * HDIM + lch * 8);
            gld_lds16(&Vs[buf][r0 * 64], Vp + (size_t)row * SEQ + kb + lch * 8);
        }
    };

    // sub-tile 0: q-tile j (keys kt<=j); sub-tile 1: q-tile 31-j (all kt)
    const int q0s[2] = { j * 64 + wave * 16, (31 - j) * 64 + wave * 16 };

    bf16x8 qf[2][2];
#pragma unroll
    for (int qq = 0; qq < 2; qq++) {
        qf[qq][0] = *(const bf16x8*)&Qp[(size_t)(q0s[qq] + lane15) * HDIM + quad * 8];
        qf[qq][1] = *(const bf16x8*)&Qp[(size_t)(q0s[qq] + lane15) * HDIM + 32 + quad * 8];
    }

    float lrow[2] = {0.f, 0.f};
    f32x4 oT[2][4];
#pragma unroll
    for (int qq = 0; qq < 2; qq++)
#pragma unroll
        for (int t = 0; t < 4; t++) oT[qq][t] = (f32x4){0.f, 0.f, 0.f, 0.f};

    const int nT = 32 - j;                   // stagings: B's full key range
    issueKV(0, 0);

    for (int kt = 0; kt < nT; kt++) {
        const int buf = kt & 1;
        __syncthreads();                                   // tile kt ready
        if (kt + 1 < nT) issueKV((kt + 1) * 64, buf ^ 1);  // prefetch

        const int kb = kt * 64;

        // hoist K fragments once per tile; shared by both q-sub-tiles
        bf16x8 kf[4][2];
#pragma unroll
        for (int kg = 0; kg < 4; kg++) {
            int row = kg * 16 + lane15;
            kf[kg][0] = *(const bf16x8*)&Ks[buf][row * 64 + ((quad    ) ^ (row & 7)) * 8];
            kf[kg][1] = *(const bf16x8*)&Ks[buf][row * 64 + ((quad + 4) ^ (row & 7)) * 8];
        }

#pragma unroll
        for (int qq = 0; qq < 2; qq++) {
            const int q0q = q0s[qq];
            if (qq == 0 && kt > j) continue;   // A done (wave-uniform branch)

            // QK^T -> S^T[key][query]: A = K fragment, B = Q fragment
            f32x4 sT[4];
            __builtin_amdgcn_s_setprio(1);
#pragma unroll
            for (int kg = 0; kg < 4; kg++) {
                sT[kg] = (f32x4){0.f, 0.f, 0.f, 0.f};
                sT[kg] = __builtin_amdgcn_mfma_f32_16x16x32_bf16(kf[kg][0], qf[qq][0], sT[kg], 0, 0, 0);
                sT[kg] = __builtin_amdgcn_mfma_f32_16x16x32_bf16(kf[kg][1], qf[qq][1], sT[kg], 0, 0, 0);
            }
            __builtin_amdgcn_s_setprio(0);

            // causal mask: only the diagonal tile (wave-uniform test)
            if (kb + 64 > q0q) {
                const int query = q0q + lane15;
#pragma unroll
                for (int kg = 0; kg < 4; kg++) {
                    int key0 = kb + kg * 16 + quad * 4;
#pragma unroll
                    for (int r = 0; r < 4; r++)
                        sT[kg][r] = (key0 + r <= query) ? sT[kg][r] : -1e30f;
                }
            }

            // unnormalized softmax: P^T = exp2(S^T); l += sum; pack to bf16
            bf16x4 pf[4];
#pragma unroll
            for (int kg = 0; kg < 4; kg++) {
#pragma unroll
                for (int r = 0; r < 4; r++) sT[kg][r] = fast_exp2(sT[kg][r]);
                lrow[qq] += (sT[kg][0] + sT[kg][1]) + (sT[kg][2] + sT[kg][3]);
                bf16x4 v;
#pragma unroll
                for (int r = 0; r < 4; r++) v[r] = (bf16_t)sT[kg][r];
                pf[kg] = v;
            }

            // PV: O^T[d][q] += V^T[d][k] * P^T[k][q], 16x16x16 MFMAs.
            __builtin_amdgcn_s_setprio(1);
#pragma unroll
            for (int t = 0; t < 4; t++) {
                int vrow = t * 16 + lane15;
#pragma unroll
                for (int kg = 0; kg < 4; kg++) {
                    int c    = kg * 2 + (quad >> 1);           // logical 8-elem chunk
                    int phys = c ^ (vrow & 7);
                    bf16x4 vf = *(const bf16x4*)&Vs[buf][vrow * 64 + phys * 8 + (quad & 1) * 4];
                    oT[qq][t] = mfma16_bf16(vf, pf[kg], oT[qq][t]);
                }
            }
            __builtin_amdgcn_s_setprio(0);
        }
    }

    // epilogue per sub-tile: l-reduce, O^T -> LDS -> coalesced global write
#pragma unroll
    for (int qq = 0; qq < 2; qq++) {
        const int q0q = q0s[qq];
        float l = lrow[qq];
        l += __shfl_xor(l, 16, 64);
        l += __shfl_xor(l, 32, 64);
        const float inv = 1.0f / l;

#pragma unroll
        for (int t = 0; t < 4; t++)
#pragma unroll
            for (int r = 0; r < 4; r++)
                pl[lane15 * 72 + t * 16 + quad * 4 + r] = (bf16_t)(oT[qq][t][r] * inv);

        const int qrow = lane >> 2;      // 0..15 query within sub-tile
        const int ch   = lane & 3;       // 8-elem d-chunk
        bf16_t* orow = &obuf[((size_t)(b * SEQ + q0q + qrow)) * EMB + h * HDIM];
#pragma unroll
        for (int p = 0; p < 2; p++) {
            bf16x8 v = *(const bf16x8*)&pl[qrow * 72 + (ch + p * 4) * 8];
            *(bf16x8*)&orow[(ch + p * 4) * 8] = v;
        }
    }
}

// ---------------------------------------------------------------------------
extern "C" void kernel_launch(void* const* d_in, const int* in_sizes, int n_in,
                              void* d_out, int out_size, void* d_ws, size_t ws_size,
                              hipStream_t stream) {
    const float* x      = (const float*)d_in[0];
    // d_in[1] = mask: causal by construction, implemented analytically
    const float* W_attn = (const float*)d_in[2];
    const float* b_attn = (const float*)d_in[3];
    const float* W_proj = (const float*)d_in[4];
    const float* b_proj = (const float*)d_in[5];
    float* out = (float*)d_out;   // fp32 output

    bf16_t* ws  = (bf16_t*)d_ws;
    bf16_t* WaT = ws;                                         // [2304][768]
    bf16_t* WpT = WaT + (size_t)N3 * EMB;                     // [768][768]
    bf16_t* Qb  = WpT + (size_t)EMB * EMB;                    // [B*H][S][D]
    bf16_t* Kb  = Qb + (size_t)BATCH * NHEAD * SEQ * HDIM;
    bf16_t* Vt  = Kb + (size_t)BATCH * NHEAD * SEQ * HDIM;    // [B*H][D][S]
    bf16_t* Ob  = Vt + (size_t)BATCH * NHEAD * SEQ * HDIM;    // [8192][768]
    bf16_t* xb  = Ob;   // alias: bf16 x is dead before attn writes Ob

    // one prep launch: both W transposes + x convert
    prep_kernel<<<3840, 256, 0, stream>>>(W_attn, WaT, W_proj, WpT, x, xb);

    // QKV: 768 blocks (64 M x 12 N, 128x192 tile), XCD-swizzled, 3/CU exact.
    gemm_kernel<<<768, 256, 0, stream>>>(xb, WaT, b_attn, Qb, Kb, Vt);

    // attn: 768 blocks = (bh, pair {j,31-j}), merged key loop, uniform work.
    attn_kernel<<<768, 256, 0, stream>>>(Qb, Kb, Vt, Ob);

    // proj: 768 blocks (128 M x 6 N), TM=64 x TN=128, BK=64, XCD-swizzled.
    proj_kernel<<<768, 256, 0, stream>>>(Ob, WpT, b_proj, out);
}